// Round 14
// baseline (136.484 us; speedup 1.0000x reference)
//
#include <hip/hip_runtime.h>
#include <hip/hip_bf16.h>
#include <math.h>

// Self_Attention_Local R19: i-split decomposition for 2x occupancy.
//   Five scheduling nulls (R14-R18) + all pipes <30% busy prove the kernel is
//   latency-bound at the decomposition's 16-waves/CU cap (4096 (patch,head)
//   waves / 256 CUs). R19 splits each (patch,head) into TWO waves by output
//   channel half (i 0-63 / 64-127): 4096 blocks x 128 threads (2 waves) =
//   16 blocks/CU x 2 = 32 waves/CU. LDS: 5 shared 2KB zones = 10KB/block
//   (=160/16); per-wave 4KB P slabs overlay the dead zones; CTX overlays
//   w0's P region behind barriers. All swizzle keys / chunk algebra / MFMA
//   layouts reused VERBATIM from R16; only zone bases + loop extents change.
//   Stats computed redundantly per wave from shared QN/KN (no cross-wave
//   reduce). out-GEMM: shared CTX, full-i contraction, each wave owns 4 of
//   8 col-tiles; atomicAdd across heads unchanged.
//   KEPT: XCD swizzle (same-patch heads same XCD), setprio, R13 rotated
//   out-GEMM prefetch, f2bf, 6-shuffle butterfly.
//   DEAD: v_cvt_pk_bf16_f32 (R17). QUARANTINED: gh-shortcut, cross-loop
//   lookahead (R12 spill).

typedef short bfrag __attribute__((ext_vector_type(8)));   // 8 bf16 = 4 VGPRs
typedef float f32x4 __attribute__((ext_vector_type(4)));

static __device__ __forceinline__ short f2bf(float x) {
    __hip_bfloat16 h = __float2bfloat16(x);
    return __builtin_bit_cast(short, h);
}
static __device__ __forceinline__ bfrag bzero() {
    bfrag z;
    #pragma unroll
    for (int j = 0; j < 8; ++j) z[j] = 0;
    return z;
}

// ---------------- convertW: 128 blocks ----------------
__global__ __launch_bounds__(256) void convertW(
    const float* __restrict__ Wq, const float* __restrict__ Wk,
    const float* __restrict__ Wv, const float* __restrict__ Wout,
    short* __restrict__ Wp, short* __restrict__ Wout_pt,
    float* __restrict__ out)
{
    __shared__ short lt[128 * 33];          // union: [32][129] or [128][33]
    const int b = blockIdx.x, t = threadIdx.x;

    // zero out: 524288 floats = 131072 float4 = 128 blocks x 1024
    {
        float4* o4 = (float4*)out;
        const int zb = b * 1024 + t;
        #pragma unroll
        for (int k = 0; k < 4; ++k)
            o4[zb + k * 256] = make_float4(0.f, 0.f, 0.f, 0.f);
    }

    if (b < 96) {
        const int x = b >> 5, h = (b >> 2) & 7, k0 = (b & 3) * 32;
        const float* W = (x == 0) ? Wq : (x == 1) ? Wk : Wv;
        #pragma unroll 4
        for (int rr = 0; rr < 16; ++rr) {
            const int k = rr * 2 + (t >> 7);          // 0..31
            const int i = t & 127;
            lt[k * 129 + i] = f2bf(W[(k0 + k) * 1024 + i * 8 + h]);
        }
        __syncthreads();
        short* dst = Wp + (x * 8 + h) * 16384;
        #pragma unroll
        for (int pp = 0; pp < 4; ++pp) {
            const int i  = pp * 32 + (t >> 3);
            const int kk = (t & 7) * 4;
            short4 v;
            v.x = lt[(kk + 0) * 129 + i]; v.y = lt[(kk + 1) * 129 + i];
            v.z = lt[(kk + 2) * 129 + i]; v.w = lt[(kk + 3) * 129 + i];
            *(short4*)&dst[i * 128 + k0 + kk] = v;
        }
    } else {
        const int b2 = b - 96, h = b2 >> 2, c0 = (b2 & 3) * 32;
        #pragma unroll 4
        for (int rr = 0; rr < 16; ++rr) {
            const int i = rr * 8 + (t >> 5);
            const int c = t & 31;
            lt[i * 33 + c] = f2bf(Wout[(i * 8 + h) * 128 + c0 + c]);
        }
        __syncthreads();
        short* dst = Wout_pt + h * 16384;
        #pragma unroll
        for (int pp = 0; pp < 4; ++pp) {
            const int c  = pp * 8 + (t >> 5);
            const int i0 = (t & 31) * 4;
            short4 v;
            v.x = lt[(i0 + 0) * 33 + c]; v.y = lt[(i0 + 1) * 33 + c];
            v.z = lt[(i0 + 2) * 33 + c]; v.w = lt[(i0 + 3) * 33 + c];
            *(short4*)&dst[(c0 + c) * 128 + i0] = v;
        }
    }
}

// ---------------- attn4 ----------------
// Block = (patch pt, head h), 128 threads = 2 waves (w = i-half).
// LDS zones (shorts), 10 KB total, all per-PATCH (shared by the 2 waves):
//   QT [0..1023]     Qt[i][p]   (dies after bs hoist -> w0 P chunks 0,1; CTX)
//   KT [1024..2047]  Kt[j][p]   (live through band loop)
//   QN [2048..3071]  Q natural  (dies after Gram -> w0 P chunks 2,3)
//   KN [3072..4095]  K natural  (dies after Gram -> w1 P chunks 0,1)
//   VS [4096..5119]  V natural  (dies after av hoist -> w1 P chunks 2,3)
// P per wave: 4 chunks of 512 shorts ([16 i][32 j] each), own zones only.
// CTX [p][i] 1024 shorts -> QT space after barrier3.
#define QT2  0
#define KT2  1024
#define QN2  2048
#define KN2  3072
#define VS2  4096

__global__ __launch_bounds__(128, 6) void attn4(
    const float* __restrict__ emb,      // [4096][128] fp32
    const short* __restrict__ Wp,       // [3][8][128 i][128 k]
    const short* __restrict__ Wout_pt,  // [8][128 col][128 i]
    float* __restrict__ out)            // [4096][128] fp32, atomic target
{
    __shared__ short lds[5120];         // 10 KB -> 16 blocks/CU
    const int bid = blockIdx.x;         // 0..4095
    // XCD swizzle: heads of one patch share bid mod 8 -> same XCD
    const int pt  = bid & 511;          // patch 0..511
    const int h   = bid >> 9;           // head 0..7
    const int t   = threadIdx.x;
    const int w    = t >> 6;            // wave 0..1 (i-half)
    const int lane = t & 63;
    const int m16  = lane & 15;
    const int quad = lane >> 4;
    const int q8   = quad * 8;

    // ====== QKV: (8x128) @ W_h (128x128) x3, split 12 tiles per wave ======
    {
        bfrag a[4];                      // emb rows (8 tokens), rows 8-15 zero
        #pragma unroll
        for (int ks = 0; ks < 4; ++ks) {
            if (m16 < 8) {
                const float* er = emb + (size_t)(pt*8 + m16) * 128 + ks*32 + q8;
                const float4 x0 = *(const float4*)er;
                const float4 x1 = *(const float4*)(er + 4);
                bfrag f;
                f[0]=f2bf(x0.x); f[1]=f2bf(x0.y); f[2]=f2bf(x0.z); f[3]=f2bf(x0.w);
                f[4]=f2bf(x1.x); f[5]=f2bf(x1.y); f[6]=f2bf(x1.z); f[7]=f2bf(x1.w);
                a[ks] = f;
            } else
                a[ks] = bzero();
        }

        #pragma unroll 1
        for (int tt = 0; tt < 12; ++tt) {
            const int nt = w * 12 + tt;           // 0..23 = {q,k,v} x 8 i-tiles
            const int x  = nt >> 3;
            const int i0 = (nt & 7) * 16;
            const short* Wb = Wp + ((x*8 + h)*128 + i0 + m16) * 128;
            bfrag bb[4];
            #pragma unroll
            for (int ks = 0; ks < 4; ++ks)
                bb[ks] = *(const bfrag*)&Wb[ks*32 + q8];
            f32x4 c0 = {0.f,0.f,0.f,0.f};
            __builtin_amdgcn_s_setprio(1);
            #pragma unroll
            for (int ks = 0; ks < 4; ++ks)
                c0 = __builtin_amdgcn_mfma_f32_16x16x32_bf16(a[ks], bb[ks], c0, 0,0,0);
            __builtin_amdgcn_s_setprio(0);
            if (quad < 2) {                       // rows p = quad*4 + r (0..7)
                const int p0 = quad * 4;
                const int cb = nt & 7;
                if (x == 0) {
                    short4 v;
                    v.x = f2bf(c0[0]); v.y = f2bf(c0[1]);
                    v.z = f2bf(c0[2]); v.w = f2bf(c0[3]);
                    *(short4*)&lds[QT2 + (i0 + m16)*8 + p0] = v;     // Qt[i][p]
                    #pragma unroll
                    for (int r = 0; r < 4; ++r)   // Qn[p][i], key p&3 = r
                        lds[QN2 + (p0 + r)*128 + ((cb ^ r) << 4) + m16] = f2bf(c0[r]);
                } else if (x == 1) {
                    short4 v;
                    v.x = f2bf(c0[0]); v.y = f2bf(c0[1]);
                    v.z = f2bf(c0[2]); v.w = f2bf(c0[3]);
                    *(short4*)&lds[KT2 + (i0 + m16)*8 + p0] = v;     // Kt[j][p]
                    #pragma unroll
                    for (int r = 0; r < 4; ++r)   // Kn[p][j], key p&3 = r
                        lds[KN2 + (p0 + r)*128 + ((cb ^ r) << 4) + m16] = f2bf(c0[r]);
                } else {
                    #pragma unroll
                    for (int r = 0; r < 4; ++r)   // Vs[p][j], key p>>2 = quad
                        lds[VS2 + (p0 + r)*128 + ((cb ^ quad) << 4) + m16] = f2bf(c0[r]);
                }
            }
        }
    }
    __syncthreads();   // barrier 1: Q/K/V halves exchanged between the 2 waves

    // ===== stats via Grams (both waves redundantly; shared QN/KN) =========
    float rs2, nbias;
    {
        bfrag gq[4], gk[4], gs[4], ones;
        #pragma unroll
        for (int j = 0; j < 8; ++j) ones[j] = (short)0x3F80;   // bf16 1.0
        #pragma unroll
        for (int ks = 0; ks < 4; ++ks) {
            const int bswz = (((2*ks + (quad >> 1)) ^ (m16 & 3)) << 4) + (quad & 1)*8;
            gq[ks] = (m16 < 8) ? *(const bfrag*)&lds[QN2 + m16*128 + bswz] : bzero();
            gk[ks] = (m16 < 8) ? *(const bfrag*)&lds[KN2 + m16*128 + bswz] : bzero();
            gs[ks] = (m16 < 8) ? *(const bfrag*)&lds[QN2 + m16*128 + bswz]
                               : *(const bfrag*)&lds[KN2 + (m16 - 8)*128 + bswz];
        }
        f32x4 cg = {0.f,0.f,0.f,0.f}, ch = {0.f,0.f,0.f,0.f}, cs = {0.f,0.f,0.f,0.f};
        __builtin_amdgcn_s_setprio(1);
        #pragma unroll
        for (int ks = 0; ks < 4; ++ks) {
            cg = __builtin_amdgcn_mfma_f32_16x16x32_bf16(gq[ks], gq[ks], cg, 0,0,0);
            ch = __builtin_amdgcn_mfma_f32_16x16x32_bf16(gk[ks], gk[ks], ch, 0,0,0);
            cs = __builtin_amdgcn_mfma_f32_16x16x32_bf16(gs[ks], ones,  cs, 0,0,0);
        }
        __builtin_amdgcn_s_setprio(0);
        float gh = 0.f, sp = 0.f;
        #pragma unroll
        for (int r = 0; r < 4; ++r) {
            gh = fmaf(cg[r], ch[r], gh);
            sp = fmaf(cs[r], __shfl_xor(cs[r], 32), sp);     // sQ[p]*sK[p]
        }
        sp += __shfl_xor(sp, 16);
        #pragma unroll
        for (int off = 1; off <= 32; off <<= 1)
            gh += __shfl_xor(gh, off);
        const float mean = sp * (1.f / 16384.f);
        const float var  = gh * (1.f / 16384.f) - mean * mean;
        rs2   = rsqrtf(var + 1e-5f) * 1.44269504f;           // fold log2(e)
        nbias = -mean * rs2;
    }

    // ===== hoist Qt B-frags (own i-half) and V A-frags ====================
    bfrag bs[4], av[4];
    #pragma unroll
    for (int nt = 0; nt < 4; ++nt)
        bs[nt] = (quad == 0)
            ? *(const bfrag*)&lds[QT2 + (w*64 + nt*16 + m16)*8] : bzero();
    #pragma unroll
    for (int ks = 0; ks < 4; ++ks) {
        if (m16 < 8) {
            const int g = (((2*ks + (quad >> 1)) ^ (m16 >> 2)) << 4) + (quad & 1)*8;
            av[ks] = *(const bfrag*)&lds[VS2 + m16*128 + g];
        } else if (m16 == 8) {                 // ones ROW -> C[8][i] = rowsum_i
            bfrag o;
            #pragma unroll
            for (int j = 0; j < 8; ++j) o[j] = (short)0x3F80;
            av[ks] = o;
        } else
            av[ks] = bzero();
    }
    __syncthreads();   // barrier 2: all QT/QN/KN/VS reads done -> P may overlay

    // ===== band loop: 8 bands of j, 4 i-tiles per wave; P in dead zones ====
    // P chunk (w,nt): w0 -> QT/QN, w1 -> KN/VS; [16 i][32 j] = 512 shorts.
    const int key2 = m16 >> 2;
    const int rowoff = m16 * 32;
    f32x4 cc[4];
    #pragma unroll
    for (int nt = 0; nt < 4; ++nt) cc[nt] = (f32x4){0.f,0.f,0.f,0.f};

    #pragma unroll
    for (int ks = 0; ks < 4; ++ks) {
        #pragma unroll
        for (int jb = 0; jb < 2; ++jb) {
            const int band = ks*2 + jb;
            const bfrag amk = (quad == 0)
                ? *(const bfrag*)&lds[KT2 + (band*16 + m16)*8] : bzero();
            const int tw = (((jb*2 + (quad >> 1)) ^ key2) << 3) + (quad & 1)*4;
            #pragma unroll
            for (int nt = 0; nt < 4; ++nt) {
                const int pbase = (w == 0) ? ((nt >> 1) ? QN2 : QT2)
                                           : ((nt >> 1) ? VS2 : KN2);
                f32x4 z = {0.f,0.f,0.f,0.f};
                __builtin_amdgcn_s_setprio(1);
                const f32x4 s4 = __builtin_amdgcn_mfma_f32_16x16x32_bf16(amk, bs[nt], z, 0,0,0);
                __builtin_amdgcn_s_setprio(0);
                short4 v;
                v.x = f2bf(__builtin_amdgcn_exp2f(fmaf(s4[0], rs2, nbias)));
                v.y = f2bf(__builtin_amdgcn_exp2f(fmaf(s4[1], rs2, nbias)));
                v.z = f2bf(__builtin_amdgcn_exp2f(fmaf(s4[2], rs2, nbias)));
                v.w = f2bf(__builtin_amdgcn_exp2f(fmaf(s4[3], rs2, nbias)));
                *(short4*)&lds[pbase + (nt & 1)*512 + rowoff + tw] = v;
            }
        }
        __builtin_amdgcn_s_setprio(1);
        #pragma unroll
        for (int nt = 0; nt < 4; ++nt) {
            const int pbase = (w == 0) ? ((nt >> 1) ? QN2 : QT2)
                                       : ((nt >> 1) ? VS2 : KN2);
            const bfrag bp = *(const bfrag*)
                &lds[pbase + (nt & 1)*512 + rowoff + ((quad ^ key2) << 3)];
            cc[nt] = __builtin_amdgcn_mfma_f32_16x16x32_bf16(av[ks], bp, cc[nt], 0,0,0);
        }
        __builtin_amdgcn_s_setprio(0);
    }

    __syncthreads();   // barrier 3: both waves' PV done -> CTX may overlay QT

    // ===== normalize once; ctx[p][i] -> QT space (shared, both halves) =====
    #pragma unroll
    for (int nt = 0; nt < 4; ++nt) {
        const float s  = __shfl(cc[nt][0], 32 + m16);   // C[8][i] from quad-2
        const float is = 1.0f / s;
        if (quad < 2) {
            #pragma unroll
            for (int r = 0; r < 4; ++r) {
                const int p = quad*4 + r;
                lds[p*128 + (((w*4 + nt) ^ (p & 3)) << 4) + m16] =
                    f2bf(cc[nt][r] * is);
            }
        }
    }
    __syncthreads();   // barrier 4: full CTX visible to both waves

    // ===== out-GEMM: ctx^T (8x128) @ Wout_h, wave owns 4 of 8 col-tiles ====
    bfrag ac[4];
    #pragma unroll
    for (int ks = 0; ks < 4; ++ks)
        ac[ks] = (m16 < 8)
            ? *(const bfrag*)&lds[m16*128
                  + (((2*ks + (quad >> 1)) ^ (m16 & 3)) << 4) + (quad & 1)*8]
            : bzero();
    const short* Wo = Wout_pt + h * 16384;
    // output row permute: pat = pt -> (bb,dd,hh,ww); p = quad*4+r -> p1p2p3
    const int bb2 = pt >> 5, rem = pt & 31;
    const int dd = rem >> 4, hh2 = (rem >> 2) & 3, ww2 = rem & 3;

    bfrag wbA[4], wbB[4];
    #pragma unroll
    for (int ks = 0; ks < 4; ++ks)
        wbA[ks] = *(const bfrag*)&Wo[(w*64 + m16)*128 + ks*32 + q8];
    #pragma unroll 1
    for (int n = 0; n < 4; ++n) {
        const int ct = w*4 + n;                 // col-tile 0..7
        if (n < 3) {
            #pragma unroll
            for (int ks = 0; ks < 4; ++ks)
                wbB[ks] = *(const bfrag*)&Wo[((ct+1)*16 + m16)*128 + ks*32 + q8];
        }
        f32x4 cc2 = {0.f,0.f,0.f,0.f};
        __builtin_amdgcn_s_setprio(1);
        #pragma unroll
        for (int ks = 0; ks < 4; ++ks)
            cc2 = __builtin_amdgcn_mfma_f32_16x16x32_bf16(ac[ks], wbA[ks], cc2, 0,0,0);
        __builtin_amdgcn_s_setprio(0);
        if (quad < 2) {
            #pragma unroll
            for (int r = 0; r < 4; ++r) {
                const int orow = bb2*256
                    + ((((dd*2 + quad)*4 + hh2)*2 + (r >> 1))*4 + ww2)*2 + (r & 1);
                atomicAdd(&out[(size_t)orow*128 + ct*16 + m16], cc2[r]);
            }
        }
        #pragma unroll
        for (int ks = 0; ks < 4; ++ks)
            wbA[ks] = wbB[ks];
    }
}

extern "C" void kernel_launch(void* const* d_in, const int* in_sizes, int n_in,
                              void* d_out, int out_size, void* d_ws, size_t ws_size,
                              hipStream_t stream) {
    const float* emb  = (const float*)d_in[0];   // (512, 8, 128)
    const float* Wq   = (const float*)d_in[1];   // (128, 1024)
    const float* Wk   = (const float*)d_in[2];
    const float* Wv   = (const float*)d_in[3];
    const float* Wout = (const float*)d_in[4];   // (1024, 128)
    float* out = (float*)d_out;                  // 524288 floats

    short* Wp      = (short*)d_ws;               // 768 KB
    short* Wout_pt = Wp + 393216;                // 256 KB

    convertW<<<128, 256, 0, stream>>>(Wq, Wk, Wv, Wout, Wp, Wout_pt, out);
    attn4<<<4096, 128, 0, stream>>>(emb, Wp, Wout_pt, out);
}